// Round 11
// baseline (239.818 us; speedup 1.0000x reference)
//
#include <hip/hip_runtime.h>
#include <hip/hip_bf16.h>

#define NN 1024
#define HID 128
#define NHEADS 4
#define HDD 32
#define NL 3

// ---- ws layout (float-word units) ----
constexpr int OFF_CONV = 16;
constexpr int OFF_NF   = OFF_CONV;            // 3072
constexpr int OFF_WP   = OFF_NF  + 3072;      // 384
constexpr int OFF_BP   = OFF_WP  + 384;       // 128
constexpr int OFF_WL   = OFF_BP  + 128;       // 49152
constexpr int OFF_WR   = OFF_WL  + 49152;     // 49152
constexpr int OFF_WVW  = OFF_WR  + 49152;     // 49152
constexpr int OFF_ATT  = OFF_WVW + 49152;     // 96
constexpr int OFF_GAM  = OFF_ATT + 96;        // 384
constexpr int OFF_BET  = OFF_GAM + 384;       // 384
constexpr int OFF_WN1  = OFF_BET + 384;       // 8192
constexpr int OFF_BN1  = OFF_WN1 + 8192;      // 64
constexpr int OFF_WN2  = OFF_BN1 + 64;        // 64
constexpr int OFF_BN2  = OFF_WN2 + 64;        // 1
constexpr int OFF_WD1  = OFF_BN2 + 1;         // 8192
constexpr int OFF_BD1  = OFF_WD1 + 8192;      // 64
constexpr int OFF_WD2  = OFF_BD1 + 64;        // 128
constexpr int OFF_BD2  = OFF_WD2 + 128;       // 2
constexpr int OFF_WV1  = OFF_BD2 + 2;         // 8192
constexpr int OFF_BV1  = OFF_WV1 + 8192;      // 64
constexpr int OFF_WV2  = OFF_BV1 + 64;        // 64
constexpr int OFF_BV2  = OFF_WV2 + 64;        // 1
constexpr int OFF_CONV_END = OFF_BV2 + 1;
constexpr int CONV_TOTAL = OFF_CONV_END - OFF_CONV;
constexpr int CB = (CONV_TOTAL + 255) / 256;  // convert blocks in k_pre
constexpr int OFF_MASK = 176960;              // 1024*32 uint32 words
constexpr int OFF_H    = OFF_MASK + NN*32;
constexpr int OFF_WLH  = OFF_H   + NN*HID;    // normal [i][128]
constexpr int OFF_WRH  = OFF_WLH + NN*HID;    // TRANSPOSED [dq=32][j=1024][4]
constexpr int OFF_WVH  = OFF_WRH + NN*HID;    // TRANSPOSED [dq=32][j=1024][4]
constexpr int OFF_CL   = OFF_WVH + NN*HID;    // [h][i]  0.6*att.wl
constexpr int OFF_CR   = OFF_CL  + NHEADS*NN; // [h][j]  0.6*att.wr

__device__ __forceinline__ float bf2f(unsigned short u) {
    return __uint_as_float(((unsigned)u) << 16);
}
__device__ __forceinline__ void store_out(void* out, int idx, float v, bool bf) {
    if (bf) {
        unsigned u = __float_as_uint(v);
        unsigned r = (u + 0x7FFFu + ((u >> 16) & 1u)) >> 16;
        ((unsigned short*)out)[idx] = (unsigned short)r;
    } else {
        ((float*)out)[idx] = v;
    }
}
__device__ __forceinline__ float ldraw(const void* p, int idx, bool bf) {
    return bf ? bf2f(((const unsigned short*)p)[idx]) : ((const float*)p)[idx];
}
// per-wave dtype sniff: fp32 normals have exponent field in [110,140];
// packed bf16 pairs viewed as fp32 essentially never do. Call from ALL lanes.
__device__ __forceinline__ bool detect_bf(const unsigned* nf) {
    unsigned w = nf[threadIdx.x & 63];
    int e = (int)((w >> 23) & 0xFFu);
    unsigned long long b = __ballot(e >= 110 && e <= 140);
    return __popcll(b) < 32;
}

struct P21 { const void* p[21]; };
__device__ const int g_sizes[21] = {3072,384,128,49152,49152,49152,96,384,384,
                                    8192,64,64,1,8192,64,128,2,8192,64,64,1};
__device__ const int g_dsts[21] = {OFF_NF,OFF_WP,OFF_BP,OFF_WL,OFF_WR,OFF_WVW,OFF_ATT,
                                   OFF_GAM,OFF_BET,OFF_WN1,OFF_BN1,OFF_WN2,OFF_BN2,
                                   OFF_WD1,OFF_BD1,OFF_WD2,OFF_BD2,OFF_WV1,OFF_BV1,
                                   OFF_WV2,OFF_BV2};

// ---- fused prologue: param convert | adj->bitmask | h0  (all independent:
// h0 reads RAW nf/Wp/bp with its own bf16 handling, so no ordering needed) ----
__global__ __launch_bounds__(256) void k_pre(P21 in, const void* adj, const unsigned* nf, float* ws) {
    bool bf = detect_bf(nf);
    int b = blockIdx.x, t = threadIdx.x;
    if (b < CB) {
        // convert all non-adj params to fp32 in ws
        int g = b * 256 + t;
        if (g >= CONV_TOTAL) return;
        int rem = g, s = 0;
        while (s < 21 && rem >= g_sizes[s]) { rem -= g_sizes[s]; s++; }
        if (s >= 21) return;
        ws[g_dsts[s] + rem] = ldraw(in.p[s], rem, bf);
    } else if (b < CB + NN) {
        // adj row -> packed bitmask
        int i = b - CB;
        unsigned* mask = (unsigned*)(ws + OFF_MASK);
        int lane = t & 63, wv = t >> 6;
        #pragma unroll
        for (int q = 0; q < 4; q++) {
            int seg = wv * 4 + q;
            int j = seg * 64 + lane;
            float v = ldraw(adj, i * NN + j, bf);
            unsigned long long bl = __ballot(v > 0.5f);
            if (lane == 0) {
                mask[i * 32 + seg * 2]     = (unsigned)bl;
                mask[i * 32 + seg * 2 + 1] = (unsigned)(bl >> 32);
            }
        }
    } else {
        // h0 = relu(nf @ Wp + bp), raw reads: 2 nodes per block
        int bb = b - CB - NN;
        int i = bb * 2 + (t >> 7), c = t & 127;
        float a = ldraw(in.p[2], c, bf);                     // bp
        #pragma unroll
        for (int k = 0; k < 3; k++)
            a += ldraw(in.p[0], i * 3 + k, bf) * ldraw(in.p[1], k * HID + c, bf);
        ws[OFF_H + i * HID + c] = fmaxf(a, 0.0f);
    }
}

// ---- per layer: wlh = h@Wl (normal + cl), wrh/wvh = h@{Wr,Wv} (transposed + cr) ----
__global__ __launch_bounds__(128) void k_mm3(float* ws, int l) {
    __shared__ float hs[4][HID];
    int c = threadIdx.x, i0 = blockIdx.x * 4, which = blockIdx.y;
    const float* h = ws + OFF_H;
    #pragma unroll
    for (int r = 0; r < 4; r++) hs[r][c] = h[(i0 + r) * HID + c];
    __syncthreads();
    int woff = (which == 0) ? OFF_WL : (which == 1) ? OFF_WR : OFF_WVW;
    const float* W = ws + woff + l * HID * HID;
    float a[4] = {0,0,0,0};
    #pragma unroll 4
    for (int k = 0; k < HID; k++) {
        float w = W[k * HID + c];
        #pragma unroll
        for (int r = 0; r < 4; r++) a[r] += hs[r][k] * w;
    }
    if (which == 0) {
        #pragma unroll
        for (int r = 0; r < 4; r++) ws[OFF_WLH + (i0 + r) * HID + c] = a[r];
        float att = ws[OFF_ATT + l * HDD + (c & 31)];
        #pragma unroll
        for (int r = 0; r < 4; r++) {
            float t = att * a[r];
            #pragma unroll
            for (int off = 1; off < 32; off <<= 1) t += __shfl_xor(t, off, 64);
            if ((c & 31) == 0) ws[OFF_CL + (c >> 5) * NN + (i0 + r)] = 0.6f * t;
        }
    } else {
        int doff = (which == 1) ? OFF_WRH : OFF_WVH;
        // transposed-tiled: element (j, c) -> [c>>2][j][c&3]
        #pragma unroll
        for (int r = 0; r < 4; r++)
            ws[doff + (c >> 2) * (NN * 4) + (i0 + r) * 4 + (c & 3)] = a[r];
        if (which == 1) {
            float att = ws[OFF_ATT + l * HDD + (c & 31)];
            #pragma unroll
            for (int r = 0; r < 4; r++) {
                float t = att * a[r];
                #pragma unroll
                for (int off = 1; off < 32; off <<= 1) t += __shfl_xor(t, off, 64);
                if ((c & 31) == 0) ws[OFF_CR + (c >> 5) * NN + (i0 + r)] = 0.6f * t;
            }
        }
    }
}

// ---- per layer: fused attention, 4 nodes/block, d-SPLIT waves ----
// Block = 512 threads = 8 waves = 4 heads x 2 d-halves; grid 256 (1 block/CU).
// Wave (h,dh) streams ONLY its 16 dims (4 dq-tiles) of wr/wv but serves all 4
// nodes -> every wr/wv byte is streamed ONCE per block: L2 traffic halves,
// 512 (r5/r10) -> 256 MB/dispatch. r10 proved occupancy is a non-factor
// (2 blocks/CU: exactly 0 gain), i.e. the kernel is L2-BW-bound -> traffic is
// the only remaining lever.
// e-dot is d-split: each wave writes 64 partial dots/lane to pbuf (pad-66 ->
// 2-way bank = free), ONE barrier, then both d-half waves read own+partner
// partials -> identical full e, m, lsum (computed redundantly, no merge).
// Pass-2 acc needs NO cross-wave sum (disjoint dims) -> single reduce round.
// Register budget honored (r7/r8 AGPR-shuttle ledger): pass1 ~120, pass2 ~110
// live floats, well under the ~130 threshold.
// e_ij = 0.6*att.(wl_i+wr_j) + sum_d 0.4*att_d*|wl_id + wr_jd|  (exact leaky split)
__global__ __launch_bounds__(512) void k_attn(float* ws, int l) {
    int t = threadIdx.x;
    int i0 = blockIdx.x * 4;
    int lane = t & 63;
    int w = t >> 6;
    int h  = __builtin_amdgcn_readfirstlane(w & 3);
    int dh = __builtin_amdgcn_readfirstlane(w >> 2);

    __shared__ float pbuf[8][64][66];   // 135 KB: e-partials, then acc-reduce scratch
    __shared__ unsigned mrow[4][32];
    __shared__ float invs[4][4];        // [node][head]
    __shared__ float agg_s[4][HID];
    __shared__ float red2[4][2][2];

    if (t < 128) mrow[t >> 5][t & 31] = ((const unsigned*)(ws + OFF_MASK))[i0 * 32 + t];
    __syncthreads();

    // per-lane 16-bit adjacency masks for the 4 nodes: bit jc = adj of j=jc*64+lane
    unsigned mb[4];
    #pragma unroll
    for (int n = 0; n < 4; n++) {
        unsigned m = 0;
        #pragma unroll
        for (int jc = 0; jc < 16; jc++)
            m |= ((mrow[n][jc * 2 + (lane >> 5)] >> (lane & 31)) & 1u) << jc;
        mb[n] = m;
    }

    // wave-uniform vectors (this wave's 16 dims) -> registers (0.4 folded in)
    float att_r[16], wl[4][16], cl[4];
    const float* attp = ws + OFF_ATT + l * HDD + dh * 16;
    #pragma unroll
    for (int d = 0; d < 16; d++) att_r[d] = 0.4f * attp[d];
    #pragma unroll
    for (int n = 0; n < 4; n++) {
        const float* wlp = ws + OFF_WLH + (i0 + n) * HID + h * HDD + dh * 16;
        #pragma unroll
        for (int d = 0; d < 16; d++) wl[n][d] = wlp[d];
        cl[n] = ws[OFF_CL + h * NN + i0 + n];
    }

    const float* wrT = ws + OFF_WRH + (h * 8 + dh * 4) * (NN * 4) + lane * 4;
    const float* wvT = ws + OFF_WVH + (h * 8 + dh * 4) * (NN * 4) + lane * 4;
    const float* crp = ws + OFF_CR + h * NN;

    // pass 1: partial e-dots over this wave's 16 dims -> pbuf[w][lane][jc*4+n]
    #pragma unroll 1
    for (int jc = 0; jc < 16; jc++) {
        float cr6 = crp[jc * 64 + lane];
        float dot[4] = {0.f, 0.f, 0.f, 0.f};
        #pragma unroll
        for (int k = 0; k < 4; k++) {
            float4 w4 = *(const float4*)(wrT + k * (NN * 4) + jc * 256);
            #pragma unroll
            for (int n = 0; n < 4; n++) {
                dot[n] = fmaf(att_r[k*4+0], fabsf(wl[n][k*4+0] + w4.x), dot[n]);
                dot[n] = fmaf(att_r[k*4+1], fabsf(wl[n][k*4+1] + w4.y), dot[n]);
                dot[n] = fmaf(att_r[k*4+2], fabsf(wl[n][k*4+2] + w4.z), dot[n]);
                dot[n] = fmaf(att_r[k*4+3], fabsf(wl[n][k*4+3] + w4.w), dot[n]);
            }
        }
        #pragma unroll
        for (int n = 0; n < 4; n++) {
            float pv = dot[n];
            if (dh == 0) pv += cl[n] + cr6;   // linear terms counted exactly once
            pbuf[w][lane][jc * 4 + n] = pv;
        }
    }
    __syncthreads();   // both d-halves' partials visible

    // mini-pass: full e = own + partner partials; per-node masked lane-max.
    // Both d-half waves compute IDENTICAL m (and later lsum) -> no merge.
    int wp = w ^ 4;
    float m4[4] = {-1e30f, -1e30f, -1e30f, -1e30f};
    #pragma unroll 1
    for (int jc = 0; jc < 16; jc++) {
        #pragma unroll
        for (int n = 0; n < 4; n++) {
            float e = pbuf[w][lane][jc * 4 + n] + pbuf[wp][lane][jc * 4 + n];
            e = ((mb[n] >> jc) & 1u) ? e : -1e9f;
            m4[n] = fmaxf(m4[n], e);
        }
    }
    #pragma unroll
    for (int off = 32; off > 0; off >>= 1) {
        #pragma unroll
        for (int n = 0; n < 4; n++) m4[n] = fmaxf(m4[n], __shfl_xor(m4[n], off, 64));
    }

    // pass 2: pe = exp(e_masked - m) (masked -> exact 0), acc over 16 dims x 4 nodes
    float acc[4][16];
    #pragma unroll
    for (int n = 0; n < 4; n++)
        #pragma unroll
        for (int d = 0; d < 16; d++) acc[n][d] = 0.0f;
    float ls[4] = {0.f, 0.f, 0.f, 0.f};
    #pragma unroll 1
    for (int jc = 0; jc < 16; jc++) {
        float pe[4];
        #pragma unroll
        for (int n = 0; n < 4; n++) {
            float e = pbuf[w][lane][jc * 4 + n] + pbuf[wp][lane][jc * 4 + n];
            e = ((mb[n] >> jc) & 1u) ? e : -1e9f;
            pe[n] = __expf(e - m4[n]);
            ls[n] += pe[n];
        }
        #pragma unroll
        for (int k = 0; k < 4; k++) {
            float4 v4 = *(const float4*)(wvT + k * (NN * 4) + jc * 256);
            #pragma unroll
            for (int n = 0; n < 4; n++) {
                acc[n][k*4+0] = fmaf(pe[n], v4.x, acc[n][k*4+0]);
                acc[n][k*4+1] = fmaf(pe[n], v4.y, acc[n][k*4+1]);
                acc[n][k*4+2] = fmaf(pe[n], v4.z, acc[n][k*4+2]);
                acc[n][k*4+3] = fmaf(pe[n], v4.w, acc[n][k*4+3]);
            }
        }
    }
    #pragma unroll
    for (int off = 32; off > 0; off >>= 1) {
        #pragma unroll
        for (int n = 0; n < 4; n++) ls[n] += __shfl_xor(ls[n], off, 64);
    }
    if (dh == 0 && lane == 0) {
        #pragma unroll
        for (int n = 0; n < 4; n++) invs[n][h] = 1.0f / ls[n];
    }
    __syncthreads();   // all pbuf partial-reads done; invs visible

    // acc -> pbuf (as rbuf) [w][lane][n*16+d]; single reduce round (dims are
    // disjoint across d-half waves -> placement, not summation, across waves)
    #pragma unroll
    for (int n = 0; n < 4; n++)
        #pragma unroll
        for (int d = 0; d < 16; d++) pbuf[w][lane][n * 16 + d] = acc[n][d];
    __syncthreads();
    {
        int g = t >> 6, s = lane;      // region g = (head g&3, d-half g>>2), slot s
        float sum = 0.0f;
        #pragma unroll 8
        for (int lq = 0; lq < 64; lq++) sum += pbuf[g][lq][s];
        int gh = g & 3, gdh = g >> 2;
        int n = s >> 4, dd = s & 15;
        agg_s[n][gh * 32 + gdh * 16 + dd] = sum * invs[n][gh];
    }
    __syncthreads();

    // layernorm + residual for the 4 nodes: t -> node n=t>>7, feature f=t&127
    {
        int n = t >> 7, f = t & 127;
        float agg = agg_s[n][f];
        float s = agg, s2 = agg * agg;
        #pragma unroll
        for (int off = 32; off > 0; off >>= 1) {
            s  += __shfl_xor(s,  off, 64);
            s2 += __shfl_xor(s2, off, 64);
        }
        int half = (t >> 6) & 1;
        if (lane == 0) { red2[n][half][0] = s; red2[n][half][1] = s2; }
        __syncthreads();
        float ts  = red2[n][0][0] + red2[n][1][0];
        float ts2 = red2[n][0][1] + red2[n][1][1];
        float mu  = ts  * (1.0f / HID);
        float var = ts2 * (1.0f / HID) - mu * mu;
        float gm = ws[OFF_GAM + l * HID + f];
        float be = ws[OFF_BET + l * HID + f];
        float o = (agg - mu) * rsqrtf(var + 1e-5f) * gm + be;
        ws[OFF_H + (i0 + n) * HID + f] += fmaxf(o, 0.0f);
    }
}

// ---- fused epilogue, 1024 threads/block ----
// blocks 0..63: node_logits + delta_mu heads, 16 nodes/block (wave = node).
// block 64: pooled mean (8 row-groups x 128 rows, unroll-16 ILP) + value head.
__global__ __launch_bounds__(1024) void k_post(float* ws, const unsigned* nf, void* out) {
    bool bf = detect_bf(nf);
    int b = blockIdx.x, t = threadIdx.x;
    if (b < 64) {
        __shared__ float hrow[16][HID];
        int n = t >> 6, tt = t & 63;
        int i = b * 16 + n;
        hrow[n][tt]      = ws[OFF_H + i * HID + tt];
        hrow[n][tt + 64] = ws[OFF_H + i * HID + tt + 64];
        __syncthreads();
        const float* Wn1 = ws + OFF_WN1;
        const float* Wd1 = ws + OFF_WD1;
        float z1 = ws[OFF_BN1 + tt], zd = ws[OFF_BD1 + tt];
        #pragma unroll 4
        for (int k = 0; k < HID; k++) {
            float hk = hrow[n][k];
            z1 += hk * Wn1[k * 64 + tt];
            zd += hk * Wd1[k * 64 + tt];
        }
        z1 = fmaxf(z1, 0.0f); zd = fmaxf(zd, 0.0f);
        float lg = z1 * ws[OFF_WN2 + tt];
        float d0 = zd * ws[OFF_WD2 + tt * 2 + 0];
        float d1 = zd * ws[OFF_WD2 + tt * 2 + 1];
        #pragma unroll
        for (int off = 32; off > 0; off >>= 1) {
            lg += __shfl_xor(lg, off, 64);
            d0 += __shfl_xor(d0, off, 64);
            d1 += __shfl_xor(d1, off, 64);
        }
        if (tt == 0) {
            store_out(out, i,              lg + ws[OFF_BN2],     bf);
            store_out(out, NN + i * 2 + 0, d0 + ws[OFF_BD2 + 0], bf);
            store_out(out, NN + i * 2 + 1, d1 + ws[OFF_BD2 + 1], bf);
        }
    } else {
        __shared__ float part[8][HID];
        __shared__ float pooled[HID];
        int g = t >> 7, c = t & 127;
        float s = 0.0f;
        #pragma unroll 16
        for (int r = 0; r < 128; r++) s += ws[OFF_H + (g * 128 + r) * HID + c];
        part[g][c] = s;
        __syncthreads();
        if (t < HID) {
            float p = 0.0f;
            #pragma unroll
            for (int gg = 0; gg < 8; gg++) p += part[gg][t];
            pooled[t] = p * (1.0f / NN);
        }
        __syncthreads();
        if (t < 64) {
            float z = ws[OFF_BV1 + t];
            float z1 = 0.0f;
            #pragma unroll 8
            for (int k = 0; k < HID; k += 2) {
                z  += pooled[k]     * ws[OFF_WV1 + k * 64 + t];
                z1 += pooled[k + 1] * ws[OFF_WV1 + (k + 1) * 64 + t];
            }
            z = fmaxf(z + z1, 0.0f);
            float pv = z * ws[OFF_WV2 + t];
            #pragma unroll
            for (int off = 32; off > 0; off >>= 1) pv += __shfl_xor(pv, off, 64);
            if (t == 0) store_out(out, 3072, pv + ws[OFF_BV2], bf);
        }
    }
}

extern "C" void kernel_launch(void* const* d_in, const int* in_sizes, int n_in,
                              void* d_out, int out_size, void* d_ws, size_t ws_size,
                              hipStream_t stream) {
    float* ws = (float*)d_ws;
    const unsigned* nf = (const unsigned*)d_in[0];

    P21 ptrs;
    const int map[21] = {0,2,3,4,5,6,7,8,9,10,11,12,13,14,15,16,17,18,19,20,21};
    for (int s = 0; s < 21; s++) ptrs.p[s] = d_in[map[s]];

    // prologue: convert (CB blocks) | mask (NN blocks) | h0 (NN/2 blocks)
    k_pre<<<CB + NN + NN / 2, 256, 0, stream>>>(ptrs, d_in[1], nf, ws);

    for (int l = 0; l < NL; l++) {
        k_mm3<<<dim3(NN / 4, 3), 128, 0, stream>>>(ws, l);
        k_attn<<<NN / 4, 512, 0, stream>>>(ws, l);
    }

    k_post<<<65, 1024, 0, stream>>>(ws, nf, d_out);
}